// Round 1
// baseline (333.198 us; speedup 1.0000x reference)
//
#include <hip/hip_runtime.h>
#include <math.h>

// ---------------------------------------------------------------------------
// GCN 3x GraphConv (DGL norm='both'), N=50000, E=800000, 256->128->128->64.
// R12: replace the two-kernel LDS counting sort (bin_edges + lists_counts)
// with ONE atomic-scatter build kernel: per edge, p=atomicAdd(&cntI[dst],1);
// packed[dst*64+p]=src; atomicAdd(&cntO[src],1). List order is irrelevant
// (feeds an order-insensitive sum); 800K atomics over 50K counters (avg 16
// hits) are latency-hidden by 3125 blocks of TLP. prep pre-fills packed with
// pad idx N (zero msg row) so the gathers stay branch-free. 8 dispatches.
//   L1: M1 = f16(X*ns)@W1 ; H1s = relu(sum M1[src] *nd + b1)*ns
//   L2: agg2 = sum H1s[src] ; H2s = relu((agg2@W2)*nd + b2)*ns
//   L3: M3 = H2s@W3 ; out = sum M3[src]*nd + b3
// ---------------------------------------------------------------------------

typedef _Float16 half8 __attribute__((ext_vector_type(8)));
typedef float floatx4 __attribute__((ext_vector_type(4)));

#define PKW  64      // packed list width per node = 128B line

// ---- prep: weight transposes + zero counters + pad-fill packed lists ----
// i < N*PKW/8 (=400000): pad-fill packed (16B stores)
// i < N: zero cntI/cntO; i < 128: zero Bh0/Bh1 pad rows; transposes.
__global__ __launch_bounds__(256) void prep(
    const float* __restrict__ W1, const float* __restrict__ W2,
    const float* __restrict__ W3, _Float16* __restrict__ WT1,
    _Float16* __restrict__ WT2, _Float16* __restrict__ WT3,
    int* __restrict__ cntI, int* __restrict__ cntO,
    unsigned short* __restrict__ packed, int N,
    _Float16* __restrict__ z0, _Float16* __restrict__ z1,
    unsigned short padv)
{
    const int i = blockIdx.x * 256 + threadIdx.x;
    const int NPK = N * (PKW / 8);           // 400000 16B stores
    if (i < NPK) {
        unsigned int pp = (unsigned int)padv | ((unsigned int)padv << 16);
        uint4 v; v.x = pp; v.y = pp; v.z = pp; v.w = pp;
        ((uint4*)packed)[i] = v;
    }
    if (i < N) { cntI[i] = 0; cntO[i] = 0; }
    if (i < 128) { z0[i] = (_Float16)0.f; z1[i] = (_Float16)0.f; }
    if (i < 256 * 128) {
        int k = i >> 7, n = i & 127;
        WT1[(size_t)n * 256 + k] = (_Float16)W1[i];
    }
    if (i < 128 * 128) {
        int k = i >> 7, n = i & 127;
        WT2[(size_t)n * 128 + k] = (_Float16)W2[i];
    }
    if (i < 128 * 64) {
        int k = i >> 6, n = i & 63;
        WT3[(size_t)n * 128 + k] = (_Float16)W3[i];
    }
}

// ---- build: direct atomic scatter of per-node in-lists + degree counts ----
__global__ __launch_bounds__(256) void build_graph(
    const int* __restrict__ src, const int* __restrict__ dst, int E,
    int* __restrict__ cntI, int* __restrict__ cntO,
    unsigned short* __restrict__ packed)
{
    const int i = blockIdx.x * 256 + threadIdx.x;
    if (i >= E) return;
    const int s = src[i], d = dst[i];
    atomicAdd(&cntO[s], 1);                       // out-degree (no return use)
    const int p = atomicAdd(&cntI[d], 1);         // slot in d's in-list
    if (p < PKW)
        packed[(size_t)d * PKW + p] = (unsigned short)s;
}

// ---------------------------------------------------------------------------
// LDS-staged MFMA GEMM (verified R9/R10): C[M,NC] f16 = A[M,K] @ WT[NC,K].
// Block = 4 waves x 128 rows; wave = 2 m-tiles. B staged per 128-K chunk.
// ---------------------------------------------------------------------------
template<int K, int NC, bool A_FP32>
__global__ __launch_bounds__(256) void gemm_mfma(
    const void* __restrict__ A_, const _Float16* __restrict__ WT,
    const int* __restrict__ cnt_rs,
    const int* __restrict__ cnt_nd, const float* __restrict__ bias,
    int do_relu, const int* __restrict__ cnt_ns,
    _Float16* __restrict__ C, int M)
{
    constexpr int NT  = NC / 16;
    constexpr int KC  = 128;
    constexpr int LDW = KC + 8;
    __shared__ _Float16 Bs[NC * LDW];

    const int tid  = threadIdx.x;
    const int wave = tid >> 6;
    const int lane = tid & 63;
    const int quad = lane >> 4;
    const int l16  = lane & 15;

    const int row_base = blockIdx.x * 128 + wave * 32;
    const int ar0 = min(row_base + l16, M - 1);
    const int ar1 = min(row_base + 16 + l16, M - 1);

    floatx4 acc[2][NT];
#pragma unroll
    for (int m = 0; m < 2; m++)
#pragma unroll
        for (int t = 0; t < NT; t++)
            acc[m][t] = (floatx4){0.f, 0.f, 0.f, 0.f};

    float rs0 = 1.0f, rs1 = 1.0f;
    if (A_FP32 && cnt_rs) {
        rs0 = rsqrtf(fmaxf((float)cnt_rs[ar0], 1.0f));
        rs1 = rsqrtf(fmaxf((float)cnt_rs[ar1], 1.0f));
    }

    const float*    Af = (const float*)A_;
    const _Float16* Ah = (const _Float16*)A_;

    for (int kc = 0; kc < K; kc += KC) {
#pragma unroll
        for (int s = tid; s < NC * (KC / 8); s += 256) {
            int row  = s >> 4;
            int col8 = s & 15;
            half8 v = *(const half8*)&WT[(size_t)row * K + kc + col8 * 8];
            *(half8*)&Bs[row * LDW + col8 * 8] = v;
        }
        __syncthreads();
#pragma unroll
        for (int k0 = 0; k0 < KC; k0 += 32) {
            half8 a0, a1;
            if (A_FP32) {
                const float* p0 = &Af[(size_t)ar0 * K + kc + k0 + quad * 8];
                const float* p1 = &Af[(size_t)ar1 * K + kc + k0 + quad * 8];
                float4 f0 = *(const float4*)p0;
                float4 f1 = *(const float4*)(p0 + 4);
                float4 g0 = *(const float4*)p1;
                float4 g1 = *(const float4*)(p1 + 4);
                a0[0] = (_Float16)(f0.x * rs0); a0[1] = (_Float16)(f0.y * rs0);
                a0[2] = (_Float16)(f0.z * rs0); a0[3] = (_Float16)(f0.w * rs0);
                a0[4] = (_Float16)(f1.x * rs0); a0[5] = (_Float16)(f1.y * rs0);
                a0[6] = (_Float16)(f1.z * rs0); a0[7] = (_Float16)(f1.w * rs0);
                a1[0] = (_Float16)(g0.x * rs1); a1[1] = (_Float16)(g0.y * rs1);
                a1[2] = (_Float16)(g0.z * rs1); a1[3] = (_Float16)(g0.w * rs1);
                a1[4] = (_Float16)(g1.x * rs1); a1[5] = (_Float16)(g1.y * rs1);
                a1[6] = (_Float16)(g1.z * rs1); a1[7] = (_Float16)(g1.w * rs1);
            } else {
                a0 = *(const half8*)&Ah[(size_t)ar0 * K + kc + k0 + quad * 8];
                a1 = *(const half8*)&Ah[(size_t)ar1 * K + kc + k0 + quad * 8];
            }
#pragma unroll
            for (int t = 0; t < NT; t++) {
                half8 b = *(const half8*)&Bs[(t * 16 + l16) * LDW + k0 + quad * 8];
                acc[0][t] = __builtin_amdgcn_mfma_f32_16x16x32_f16(a0, b, acc[0][t], 0, 0, 0);
                acc[1][t] = __builtin_amdgcn_mfma_f32_16x16x32_f16(a1, b, acc[1][t], 0, 0, 0);
            }
        }
        __syncthreads();
    }

#pragma unroll
    for (int m = 0; m < 2; m++) {
#pragma unroll
        for (int t = 0; t < NT; t++) {
            int col = t * 16 + l16;
            float bv = bias ? bias[col] : 0.f;
#pragma unroll
            for (int r = 0; r < 4; r++) {
                int row_o = row_base + m * 16 + quad * 4 + r;
                if (row_o < M) {
                    float v = acc[m][t][r];
                    if (cnt_nd) v *= rsqrtf(fmaxf((float)cnt_nd[row_o], 1.0f));
                    v += bv;
                    if (do_relu) v = fmaxf(v, 0.f);
                    if (cnt_ns) v *= rsqrtf(fmaxf((float)cnt_ns[row_o], 1.0f));
                    C[(size_t)row_o * NC + col] = (_Float16)v;
                }
            }
        }
    }
}

// ---------------------------------------------------------------------------
// F=128 gather: wave/node, 4 groups x 16 lanes x half8 (16B). Lists padded
// with idx N (zero row) -> branch-free 8-deep independent loads per group.
// ---------------------------------------------------------------------------
__global__ __launch_bounds__(256) void gather128(
    const _Float16* __restrict__ msg, const int* __restrict__ cntI,
    const int* __restrict__ cntO, const unsigned short* __restrict__ packed,
    const float* __restrict__ bias, int do_relu, int use_nd, int use_ns,
    _Float16* __restrict__ out, int N)
{
    int node = (blockIdx.x * 256 + threadIdx.x) >> 6;
    if (node >= N) return;
    int lane = threadIdx.x & 63;
    int grp = lane >> 4, l16 = lane & 15;

    int len = min(cntI[node], PKW);   // raw atomic count; clamp to list cap
    const unsigned short* bl = packed + (size_t)node * PKW;
    const half8* mp = (const half8*)msg;   // 16 half8 per row

    float a[8];
#pragma unroll
    for (int h = 0; h < 8; h++) a[h] = 0.f;

    int iters = (len + 31) >> 5;
    if (iters < 1) iters = 1;
    for (int it = 0; it < iters; it++) {
        int j = it * 32 + grp;
        int s0 = bl[j],      s1 = bl[j + 4],  s2 = bl[j + 8],  s3 = bl[j + 12];
        int s4 = bl[j + 16], s5 = bl[j + 20], s6 = bl[j + 24], s7 = bl[j + 28];
        half8 v0 = mp[(size_t)s0 * 16 + l16];
        half8 v1 = mp[(size_t)s1 * 16 + l16];
        half8 v2 = mp[(size_t)s2 * 16 + l16];
        half8 v3 = mp[(size_t)s3 * 16 + l16];
        half8 v4 = mp[(size_t)s4 * 16 + l16];
        half8 v5 = mp[(size_t)s5 * 16 + l16];
        half8 v6 = mp[(size_t)s6 * 16 + l16];
        half8 v7 = mp[(size_t)s7 * 16 + l16];
#pragma unroll
        for (int h = 0; h < 8; h++)
            a[h] += (((float)v0[h] + (float)v1[h]) + ((float)v2[h] + (float)v3[h]))
                  + (((float)v4[h] + (float)v5[h]) + ((float)v6[h] + (float)v7[h]));
    }
#pragma unroll
    for (int h = 0; h < 8; h++) {
        a[h] += __shfl_xor(a[h], 16);
        a[h] += __shfl_xor(a[h], 32);
    }

    if (grp == 0) {
        float sc = use_nd ? rsqrtf(fmaxf((float)len, 1.0f)) : 1.0f;
        float pp = use_ns ? rsqrtf(fmaxf((float)cntO[node], 1.0f)) : 1.0f;
        half8 rv;
#pragma unroll
        for (int h = 0; h < 8; h++) {
            float bv = bias ? bias[l16 * 8 + h] : 0.f;
            float r = a[h] * sc + bv;
            if (do_relu) r = fmaxf(r, 0.f);
            rv[h] = (_Float16)(r * pp);
        }
        ((half8*)out)[(size_t)node * 16 + l16] = rv;
    }
}

// F=64 gather: 8 groups x 8 lanes x half8; 4 indep loads/group; fp32 out.
__global__ __launch_bounds__(256) void gather64(
    const _Float16* __restrict__ msg, const int* __restrict__ cntI,
    const unsigned short* __restrict__ packed, const float* __restrict__ bias,
    float* __restrict__ out, int N)
{
    int node = (blockIdx.x * 256 + threadIdx.x) >> 6;
    if (node >= N) return;
    int lane = threadIdx.x & 63;
    int grp = lane >> 3, l8 = lane & 7;

    int len = min(cntI[node], PKW);
    const unsigned short* bl = packed + (size_t)node * PKW;
    const half8* mp = (const half8*)msg;   // 8 half8 per row

    float a[8];
#pragma unroll
    for (int h = 0; h < 8; h++) a[h] = 0.f;

    int iters = (len + 31) >> 5;
    if (iters < 1) iters = 1;
    for (int it = 0; it < iters; it++) {
        int j = it * 32 + grp;
        int s0 = bl[j], s1 = bl[j + 8], s2 = bl[j + 16], s3 = bl[j + 24];
        half8 v0 = mp[(size_t)s0 * 8 + l8];
        half8 v1 = mp[(size_t)s1 * 8 + l8];
        half8 v2 = mp[(size_t)s2 * 8 + l8];
        half8 v3 = mp[(size_t)s3 * 8 + l8];
#pragma unroll
        for (int h = 0; h < 8; h++)
            a[h] += ((float)v0[h] + (float)v1[h]) + ((float)v2[h] + (float)v3[h]);
    }
#pragma unroll
    for (int h = 0; h < 8; h++) {
        a[h] += __shfl_xor(a[h], 8);
        a[h] += __shfl_xor(a[h], 16);
        a[h] += __shfl_xor(a[h], 32);
    }

    if (grp == 0) {
        float sc = rsqrtf(fmaxf((float)len, 1.0f));
        float4 r0, r1;
        r0.x = a[0] * sc + bias[l8 * 8 + 0];
        r0.y = a[1] * sc + bias[l8 * 8 + 1];
        r0.z = a[2] * sc + bias[l8 * 8 + 2];
        r0.w = a[3] * sc + bias[l8 * 8 + 3];
        r1.x = a[4] * sc + bias[l8 * 8 + 4];
        r1.y = a[5] * sc + bias[l8 * 8 + 5];
        r1.z = a[6] * sc + bias[l8 * 8 + 6];
        r1.w = a[7] * sc + bias[l8 * 8 + 7];
        float4* op = (float4*)&out[(size_t)node * 64 + l8 * 8];
        op[0] = r0;
        op[1] = r1;
    }
}

extern "C" void kernel_launch(void* const* d_in, const int* in_sizes, int n_in,
                              void* d_out, int out_size, void* d_ws, size_t ws_size,
                              hipStream_t stream)
{
    const float* X  = (const float*)d_in[0];
    const float* W1 = (const float*)d_in[1];
    const float* b1 = (const float*)d_in[2];
    const float* W2 = (const float*)d_in[3];
    const float* b2 = (const float*)d_in[4];
    const float* W3 = (const float*)d_in[5];
    const float* b3 = (const float*)d_in[6];
    const int*   src = (const int*)d_in[7];
    const int*   dst = (const int*)d_in[8];

    const int N = in_sizes[0] / 256;   // 50000
    const int E = in_sizes[7];         // 800000

    char* base = (char*)d_ws;
    size_t cur = 0;
    auto alloc = [&](size_t bytes) -> void* {
        void* p = base + cur;
        cur += (bytes + 255) & ~(size_t)255;
        return p;
    };
    unsigned short* packed = (unsigned short*)alloc((size_t)N * PKW * 2);
    int* cntO = (int*)alloc((size_t)N * 4);
    int* cntI = (int*)alloc((size_t)N * 4);
    _Float16* Bh0 = (_Float16*)alloc(((size_t)N + 1) * 128 * 2);  // +pad row
    _Float16* Bh1 = (_Float16*)alloc(((size_t)N + 1) * 128 * 2);
    _Float16* WT1 = (_Float16*)alloc((size_t)256 * 128 * 2);
    _Float16* WT2 = (_Float16*)alloc((size_t)128 * 128 * 2);
    _Float16* WT3 = (_Float16*)alloc((size_t)128 * 64 * 2);

    const int pblk = (N * (PKW / 8) + 255) / 256;   // 1563: packed pad-fill
    const int bblk = (E + 255) / 256;               // 3125: edge scatter
    const int gblk = (N + 127) / 128;
    const int wblk = (N + 3) / 4;

    prep<<<pblk, 256, 0, stream>>>(
        W1, W2, W3, WT1, WT2, WT3, cntI, cntO, packed, N,
        Bh0 + (size_t)N * 128, Bh1 + (size_t)N * 128, (unsigned short)N);
    build_graph<<<bblk, 256, 0, stream>>>(src, dst, E, cntI, cntO, packed);

    // ---- Layer 1 ----
    gemm_mfma<256, 128, true><<<gblk, 256, 0, stream>>>(
        X, WT1, cntO, nullptr, nullptr, 0, nullptr, Bh0, N);
    gather128<<<wblk, 256, 0, stream>>>(
        Bh0, cntI, cntO, packed, b1, 1, 1, 1, Bh1, N);      // H1s

    // ---- Layer 2 ----
    gather128<<<wblk, 256, 0, stream>>>(
        Bh1, cntI, cntO, packed, nullptr, 0, 0, 0, Bh0, N); // agg2
    gemm_mfma<128, 128, false><<<gblk, 256, 0, stream>>>(
        Bh0, WT2, nullptr, cntI, b2, 1, cntO, Bh1, N);      // H2s

    // ---- Layer 3 ----
    // M = N+1: row N of Bh1 is the maintained zero row -> writes the
    // 64-wide zero pad row for gather64 (no epilogue arrays -> no OOB).
    gemm_mfma<128, 64, false><<<(N + 1 + 127) / 128, 256, 0, stream>>>(
        Bh1, WT3, nullptr, nullptr, nullptr, 0, nullptr, Bh0, N + 1);  // M3
    gather64<<<wblk, 256, 0, stream>>>(
        Bh0, cntI, packed, b3, (float*)d_out, N);
}

// Round 2
// 297.526 us; speedup vs baseline: 1.1199x; 1.1199x over previous
//
#include <hip/hip_runtime.h>
#include <math.h>

// ---------------------------------------------------------------------------
// GCN 3x GraphConv (DGL norm='both'), N=50000, E=800000, 256->128->128->64.
// R13: two-phase build restored (R12's per-edge global atomics measured 82us:
// 19G atomics/s coherence-point ceiling + 10x write-amp on 2B scatters).
//  (a) bin_edges v2: count->global-base->direct LDS-cursor scatter to bins.
//      Drops prefix scans / LDS stage / binary search / extra store pass
//      (~20 -> ~6 ops per edge); pays ~3x write-amp on 4.8MB bins (~2-3us).
//  (b) lists v2: SPLIT=4 blocks per bucket BY NODE RANGE (64 nodes, 8KB
//      stage) -> grid 784 (was 196), serial loops 2.4x shorter, fully
//      deterministic (rescans bucket bin from L2; no atomic merge).
//  (c) gathers: 16-slot iterations (was 32) -> E[slots]/node 32.6 -> ~25,
//      -25% VMEM on Poisson(16) degrees.
//   L1: M1 = f16(X*ns)@W1 ; H1s = relu(sum M1[src] *nd + b1)*ns
//   L2: agg2 = sum H1s[src] ; H2s = relu((agg2@W2)*nd + b2)*ns
//   L3: M3 = H2s@W3 ; out = sum M3[src]*nd + b3
// ---------------------------------------------------------------------------

typedef _Float16 half8 __attribute__((ext_vector_type(8)));
typedef float floatx4 __attribute__((ext_vector_type(4)));

#define TILE  1024   // edges per bin tile (782 blocks)
#define BCAP  8192   // per-coarse-bucket capacity (avg 4096)
#define PKW   64     // packed list width per node = 128B line
#define EPT   4      // edges per thread in bin pass (TILE/256)
#define SPLIT 4      // lists blocks per bucket (64 nodes each)

// ---- pass 1: bin (src,dst) by dst>>8 AND src by src>>8, direct scatter ----
__global__ __launch_bounds__(256) void bin_edges(
    const int* __restrict__ src, const int* __restrict__ dst, int E, int NB,
    int* __restrict__ gcurD, int* __restrict__ gcurS,
    ushort2* __restrict__ binD, unsigned short* __restrict__ binS)
{
    __shared__ int lcntD[256], curD[256];
    __shared__ int lcntS[256], curS[256];

    const int tid = threadIdx.x;
    const int tile0 = blockIdx.x * TILE;
    const int tn = min(TILE, E - tile0);

    lcntD[tid] = 0;
    lcntS[tid] = 0;
    __syncthreads();

    unsigned short es[EPT], ed[EPT];
    unsigned char ebD[EPT], ebS[EPT];
    int nl = 0;
    for (int i = tid; i < tn; i += 256) {
        int s = src[tile0 + i], d = dst[tile0 + i];
        es[nl] = (unsigned short)s; ed[nl] = (unsigned short)d;
        ebD[nl] = (unsigned char)(d >> 8);
        ebS[nl] = (unsigned char)(s >> 8);
        nl++;
        atomicAdd(&lcntD[d >> 8], 1);
        atomicAdd(&lcntS[s >> 8], 1);
    }
    __syncthreads();

    if (tid < NB) {
        curD[tid] = (lcntD[tid] > 0) ? atomicAdd(&gcurD[tid], lcntD[tid]) : 0;
        curS[tid] = (lcntS[tid] > 0) ? atomicAdd(&gcurS[tid], lcntS[tid]) : 0;
    }
    __syncthreads();

    for (int j = 0; j < nl; j++) {
        int bD = ebD[j];
        int pD = atomicAdd(&curD[bD], 1);
        if (pD < BCAP) {
            ushort2 u; u.x = es[j]; u.y = ed[j];
            binD[(size_t)bD * BCAP + pD] = u;
        }
        int bS = ebS[j];
        int pS = atomicAdd(&curS[bS], 1);
        if (pS < BCAP) binS[(size_t)bS * BCAP + pS] = es[j];
    }
}

// ---- pass 2: packed in-lists (pad-filled) + cntI + cntO ----
// SPLIT blocks per bucket, each owns 64 nodes; rescans bucket bins (L2-hot)
// and filters -> deterministic, no cross-block merge.
__global__ __launch_bounds__(256) void lists_counts(
    const ushort2* __restrict__ binD, const int* __restrict__ gcurD,
    const unsigned short* __restrict__ binS, const int* __restrict__ gcurS,
    unsigned short* __restrict__ packed, int* __restrict__ cntI,
    int* __restrict__ cntO, int N, unsigned short padv)
{
    __shared__ unsigned short stage[64 * PKW];   // 8 KB
    __shared__ int lcnt[64];
    __shared__ int h[64];
    const int tid = threadIdx.x;
    const int b = blockIdx.x / SPLIT;
    const int part = blockIdx.x - b * SPLIT;
    const int nlo = (b << 8) + part * 64;        // first node of my 64

    if (tid < 64) { lcnt[tid] = 0; h[tid] = 0; }
    {
        unsigned int pp = (unsigned int)padv | ((unsigned int)padv << 16);
        uint4 v; v.x = pp; v.y = pp; v.z = pp; v.w = pp;
        for (int i = tid; i < 64 * PKW / 8; i += 256)   // 512 x 16B
            ((uint4*)stage)[i] = v;
    }
    __syncthreads();

    const int nD = min(gcurD[b], BCAP);
    const ushort2* ebD = binD + (size_t)b * BCAP;
    for (int i = tid; i < nD; i += 256) {
        ushort2 e = ebD[i];
        int ld = (int)e.y - nlo;
        if ((unsigned)ld < 64u) {
            int p = atomicAdd(&lcnt[ld], 1);
            if (p < PKW) stage[ld * PKW + p] = e.x;
        }
    }
    const int nS = min(gcurS[b], BCAP);
    const unsigned short* ebS = binS + (size_t)b * BCAP;
    for (int i = tid; i < nS; i += 256) {
        int ls = (int)ebS[i] - nlo;
        if ((unsigned)ls < 64u) atomicAdd(&h[ls], 1);
    }
    __syncthreads();

    if (tid < 64) {
        int node = nlo + tid;
        if (node < N) {
            cntI[node] = min(lcnt[tid], PKW);
            cntO[node] = h[tid];
        }
    }
    const int wave = tid >> 6, lane = tid & 63;
    for (int ld = wave; ld < 64; ld += 4) {
        int nd = nlo + ld;
        if (nd < N)
            packed[(size_t)nd * PKW + lane] = stage[ld * PKW + lane];
    }
}

// Fused weight transpose + workspace zeroing:
// gcur (512 ints), Bh0/Bh1 128-wide pad rows (128 halfs each).
__global__ __launch_bounds__(256) void wprep(
    const float* __restrict__ W1, const float* __restrict__ W2,
    const float* __restrict__ W3, _Float16* __restrict__ WT1,
    _Float16* __restrict__ WT2, _Float16* __restrict__ WT3,
    int* __restrict__ gcur, _Float16* __restrict__ z0,
    _Float16* __restrict__ z1)
{
    int i = blockIdx.x * 256 + threadIdx.x;
    if (i < 512) gcur[i] = 0;
    else if (i < 640) z0[i - 512] = (_Float16)0.f;
    else if (i < 768) z1[i - 640] = (_Float16)0.f;
    if (i < 256 * 128) {
        int k = i / 128, n = i - k * 128;
        WT1[(size_t)n * 256 + k] = (_Float16)W1[i];
    } else if (i < 256 * 128 + 128 * 128) {
        int r = i - 256 * 128;
        int k = r / 128, n = r - k * 128;
        WT2[(size_t)n * 128 + k] = (_Float16)W2[r];
    } else if (i < 256 * 128 + 128 * 128 + 128 * 64) {
        int r = i - 256 * 128 - 128 * 128;
        int k = r / 64, n = r - k * 64;
        WT3[(size_t)n * 128 + k] = (_Float16)W3[r];
    }
}

// ---------------------------------------------------------------------------
// LDS-staged MFMA GEMM (verified R9/R10): C[M,NC] f16 = A[M,K] @ WT[NC,K].
// Block = 4 waves x 128 rows; wave = 2 m-tiles. B staged per 128-K chunk.
// ---------------------------------------------------------------------------
template<int K, int NC, bool A_FP32>
__global__ __launch_bounds__(256) void gemm_mfma(
    const void* __restrict__ A_, const _Float16* __restrict__ WT,
    const int* __restrict__ cnt_rs,
    const int* __restrict__ cnt_nd, const float* __restrict__ bias,
    int do_relu, const int* __restrict__ cnt_ns,
    _Float16* __restrict__ C, int M)
{
    constexpr int NT  = NC / 16;
    constexpr int KC  = 128;
    constexpr int LDW = KC + 8;
    __shared__ _Float16 Bs[NC * LDW];

    const int tid  = threadIdx.x;
    const int wave = tid >> 6;
    const int lane = tid & 63;
    const int quad = lane >> 4;
    const int l16  = lane & 15;

    const int row_base = blockIdx.x * 128 + wave * 32;
    const int ar0 = min(row_base + l16, M - 1);
    const int ar1 = min(row_base + 16 + l16, M - 1);

    floatx4 acc[2][NT];
#pragma unroll
    for (int m = 0; m < 2; m++)
#pragma unroll
        for (int t = 0; t < NT; t++)
            acc[m][t] = (floatx4){0.f, 0.f, 0.f, 0.f};

    float rs0 = 1.0f, rs1 = 1.0f;
    if (A_FP32 && cnt_rs) {
        rs0 = rsqrtf(fmaxf((float)cnt_rs[ar0], 1.0f));
        rs1 = rsqrtf(fmaxf((float)cnt_rs[ar1], 1.0f));
    }

    const float*    Af = (const float*)A_;
    const _Float16* Ah = (const _Float16*)A_;

    for (int kc = 0; kc < K; kc += KC) {
#pragma unroll
        for (int s = tid; s < NC * (KC / 8); s += 256) {
            int row  = s >> 4;
            int col8 = s & 15;
            half8 v = *(const half8*)&WT[(size_t)row * K + kc + col8 * 8];
            *(half8*)&Bs[row * LDW + col8 * 8] = v;
        }
        __syncthreads();
#pragma unroll
        for (int k0 = 0; k0 < KC; k0 += 32) {
            half8 a0, a1;
            if (A_FP32) {
                const float* p0 = &Af[(size_t)ar0 * K + kc + k0 + quad * 8];
                const float* p1 = &Af[(size_t)ar1 * K + kc + k0 + quad * 8];
                float4 f0 = *(const float4*)p0;
                float4 f1 = *(const float4*)(p0 + 4);
                float4 g0 = *(const float4*)p1;
                float4 g1 = *(const float4*)(p1 + 4);
                a0[0] = (_Float16)(f0.x * rs0); a0[1] = (_Float16)(f0.y * rs0);
                a0[2] = (_Float16)(f0.z * rs0); a0[3] = (_Float16)(f0.w * rs0);
                a0[4] = (_Float16)(f1.x * rs0); a0[5] = (_Float16)(f1.y * rs0);
                a0[6] = (_Float16)(f1.z * rs0); a0[7] = (_Float16)(f1.w * rs0);
                a1[0] = (_Float16)(g0.x * rs1); a1[1] = (_Float16)(g0.y * rs1);
                a1[2] = (_Float16)(g0.z * rs1); a1[3] = (_Float16)(g0.w * rs1);
                a1[4] = (_Float16)(g1.x * rs1); a1[5] = (_Float16)(g1.y * rs1);
                a1[6] = (_Float16)(g1.z * rs1); a1[7] = (_Float16)(g1.w * rs1);
            } else {
                a0 = *(const half8*)&Ah[(size_t)ar0 * K + kc + k0 + quad * 8];
                a1 = *(const half8*)&Ah[(size_t)ar1 * K + kc + k0 + quad * 8];
            }
#pragma unroll
            for (int t = 0; t < NT; t++) {
                half8 b = *(const half8*)&Bs[(t * 16 + l16) * LDW + k0 + quad * 8];
                acc[0][t] = __builtin_amdgcn_mfma_f32_16x16x32_f16(a0, b, acc[0][t], 0, 0, 0);
                acc[1][t] = __builtin_amdgcn_mfma_f32_16x16x32_f16(a1, b, acc[1][t], 0, 0, 0);
            }
        }
        __syncthreads();
    }

#pragma unroll
    for (int m = 0; m < 2; m++) {
#pragma unroll
        for (int t = 0; t < NT; t++) {
            int col = t * 16 + l16;
            float bv = bias ? bias[col] : 0.f;
#pragma unroll
            for (int r = 0; r < 4; r++) {
                int row_o = row_base + m * 16 + quad * 4 + r;
                if (row_o < M) {
                    float v = acc[m][t][r];
                    if (cnt_nd) v *= rsqrtf(fmaxf((float)cnt_nd[row_o], 1.0f));
                    v += bv;
                    if (do_relu) v = fmaxf(v, 0.f);
                    if (cnt_ns) v *= rsqrtf(fmaxf((float)cnt_ns[row_o], 1.0f));
                    C[(size_t)row_o * NC + col] = (_Float16)v;
                }
            }
        }
    }
}

// ---------------------------------------------------------------------------
// F=128 gather: wave/node, 4 groups x 16 lanes x half8 (16B). Lists padded
// with idx N (zero row). 16 slots/iter (4 indep loads/group) -> ~25% less
// pad traffic than 32-slot iters on Poisson(16) degrees.
// ---------------------------------------------------------------------------
__global__ __launch_bounds__(256) void gather128(
    const _Float16* __restrict__ msg, const int* __restrict__ cntI,
    const int* __restrict__ cntO, const unsigned short* __restrict__ packed,
    const float* __restrict__ bias, int do_relu, int use_nd, int use_ns,
    _Float16* __restrict__ out, int N)
{
    int node = (blockIdx.x * 256 + threadIdx.x) >> 6;
    if (node >= N) return;
    int lane = threadIdx.x & 63;
    int grp = lane >> 4, l16 = lane & 15;

    int len = min(cntI[node], PKW);
    const unsigned short* bl = packed + (size_t)node * PKW;
    const half8* mp = (const half8*)msg;   // 16 half8 per row

    float a[8];
#pragma unroll
    for (int h = 0; h < 8; h++) a[h] = 0.f;

    int iters = (len + 15) >> 4;
    if (iters < 1) iters = 1;
    for (int it = 0; it < iters; it++) {
        int j = it * 16 + grp;
        int s0 = bl[j], s1 = bl[j + 4], s2 = bl[j + 8], s3 = bl[j + 12];
        half8 v0 = mp[(size_t)s0 * 16 + l16];
        half8 v1 = mp[(size_t)s1 * 16 + l16];
        half8 v2 = mp[(size_t)s2 * 16 + l16];
        half8 v3 = mp[(size_t)s3 * 16 + l16];
#pragma unroll
        for (int h = 0; h < 8; h++)
            a[h] += ((float)v0[h] + (float)v1[h]) + ((float)v2[h] + (float)v3[h]);
    }
#pragma unroll
    for (int h = 0; h < 8; h++) {
        a[h] += __shfl_xor(a[h], 16);
        a[h] += __shfl_xor(a[h], 32);
    }

    if (grp == 0) {
        float sc = use_nd ? rsqrtf(fmaxf((float)len, 1.0f)) : 1.0f;
        float pp = use_ns ? rsqrtf(fmaxf((float)cntO[node], 1.0f)) : 1.0f;
        half8 rv;
#pragma unroll
        for (int h = 0; h < 8; h++) {
            float bv = bias ? bias[l16 * 8 + h] : 0.f;
            float r = a[h] * sc + bv;
            if (do_relu) r = fmaxf(r, 0.f);
            rv[h] = (_Float16)(r * pp);
        }
        ((half8*)out)[(size_t)node * 16 + l16] = rv;
    }
}

// F=64 gather: 8 groups x 8 lanes x half8; 16 slots/iter; fp32 out.
__global__ __launch_bounds__(256) void gather64(
    const _Float16* __restrict__ msg, const int* __restrict__ cntI,
    const unsigned short* __restrict__ packed, const float* __restrict__ bias,
    float* __restrict__ out, int N)
{
    int node = (blockIdx.x * 256 + threadIdx.x) >> 6;
    if (node >= N) return;
    int lane = threadIdx.x & 63;
    int grp = lane >> 3, l8 = lane & 7;

    int len = min(cntI[node], PKW);
    const unsigned short* bl = packed + (size_t)node * PKW;
    const half8* mp = (const half8*)msg;   // 8 half8 per row

    float a[8];
#pragma unroll
    for (int h = 0; h < 8; h++) a[h] = 0.f;

    int iters = (len + 15) >> 4;
    if (iters < 1) iters = 1;
    for (int it = 0; it < iters; it++) {
        int j = it * 16 + grp;
        int s0 = bl[j], s1 = bl[j + 8];
        half8 v0 = mp[(size_t)s0 * 8 + l8];
        half8 v1 = mp[(size_t)s1 * 8 + l8];
#pragma unroll
        for (int h = 0; h < 8; h++)
            a[h] += (float)v0[h] + (float)v1[h];
    }
#pragma unroll
    for (int h = 0; h < 8; h++) {
        a[h] += __shfl_xor(a[h], 8);
        a[h] += __shfl_xor(a[h], 16);
        a[h] += __shfl_xor(a[h], 32);
    }

    if (grp == 0) {
        float sc = rsqrtf(fmaxf((float)len, 1.0f));
        float4 r0, r1;
        r0.x = a[0] * sc + bias[l8 * 8 + 0];
        r0.y = a[1] * sc + bias[l8 * 8 + 1];
        r0.z = a[2] * sc + bias[l8 * 8 + 2];
        r0.w = a[3] * sc + bias[l8 * 8 + 3];
        r1.x = a[4] * sc + bias[l8 * 8 + 4];
        r1.y = a[5] * sc + bias[l8 * 8 + 5];
        r1.z = a[6] * sc + bias[l8 * 8 + 6];
        r1.w = a[7] * sc + bias[l8 * 8 + 7];
        float4* op = (float4*)&out[(size_t)node * 64 + l8 * 8];
        op[0] = r0;
        op[1] = r1;
    }
}

extern "C" void kernel_launch(void* const* d_in, const int* in_sizes, int n_in,
                              void* d_out, int out_size, void* d_ws, size_t ws_size,
                              hipStream_t stream)
{
    const float* X  = (const float*)d_in[0];
    const float* W1 = (const float*)d_in[1];
    const float* b1 = (const float*)d_in[2];
    const float* W2 = (const float*)d_in[3];
    const float* b2 = (const float*)d_in[4];
    const float* W3 = (const float*)d_in[5];
    const float* b3 = (const float*)d_in[6];
    const int*   src = (const int*)d_in[7];
    const int*   dst = (const int*)d_in[8];

    const int N = in_sizes[0] / 256;   // 50000
    const int E = in_sizes[7];         // 800000
    const int NB = (N + 255) >> 8;     // 196 coarse buckets

    char* base = (char*)d_ws;
    size_t cur = 0;
    auto alloc = [&](size_t bytes) -> void* {
        void* p = base + cur;
        cur += (bytes + 255) & ~(size_t)255;
        return p;
    };
    int* gcur2 = (int*)alloc((size_t)2 * 256 * 4);
    int* gcurD = gcur2;
    int* gcurS = gcur2 + 256;
    ushort2*        binD   = (ushort2*)alloc((size_t)NB * BCAP * 4);
    unsigned short* binS   = (unsigned short*)alloc((size_t)NB * BCAP * 2);
    unsigned short* packed = (unsigned short*)alloc((size_t)N * PKW * 2);
    int* cntO = (int*)alloc((size_t)N * 4);
    int* cntI = (int*)alloc((size_t)N * 4);
    _Float16* Bh0 = (_Float16*)alloc(((size_t)N + 1) * 128 * 2);  // +pad row
    _Float16* Bh1 = (_Float16*)alloc(((size_t)N + 1) * 128 * 2);
    _Float16* WT1 = (_Float16*)alloc((size_t)256 * 128 * 2);
    _Float16* WT2 = (_Float16*)alloc((size_t)128 * 128 * 2);
    _Float16* WT3 = (_Float16*)alloc((size_t)128 * 64 * 2);

    const int tblk = (E + TILE - 1) / TILE;   // 782 tiles
    const int gblk = (N + 127) / 128;
    const int wblk = (N + 3) / 4;

    wprep<<<(256*128 + 128*128 + 128*64 + 255) / 256, 256, 0, stream>>>(
        W1, W2, W3, WT1, WT2, WT3,
        gcur2, Bh0 + (size_t)N * 128, Bh1 + (size_t)N * 128);
    bin_edges<<<tblk, 256, 0, stream>>>(src, dst, E, NB, gcurD, gcurS, binD, binS);
    lists_counts<<<NB * SPLIT, 256, 0, stream>>>(binD, gcurD, binS, gcurS,
                                                 packed, cntI, cntO, N,
                                                 (unsigned short)N);

    // ---- Layer 1 ----
    gemm_mfma<256, 128, true><<<gblk, 256, 0, stream>>>(
        X, WT1, cntO, nullptr, nullptr, 0, nullptr, Bh0, N);
    gather128<<<wblk, 256, 0, stream>>>(
        Bh0, cntI, cntO, packed, b1, 1, 1, 1, Bh1, N);      // H1s

    // ---- Layer 2 ----
    gather128<<<wblk, 256, 0, stream>>>(
        Bh1, cntI, cntO, packed, nullptr, 0, 0, 0, Bh0, N); // agg2
    gemm_mfma<128, 128, false><<<gblk, 256, 0, stream>>>(
        Bh0, WT2, nullptr, cntI, b2, 1, cntO, Bh1, N);      // H2s

    // ---- Layer 3 ----
    // M = N+1: row N of Bh1 is the maintained zero row -> writes the
    // 64-wide zero pad row for gather64 (no epilogue arrays -> no OOB).
    gemm_mfma<128, 64, false><<<(N + 1 + 127) / 128, 256, 0, stream>>>(
        Bh1, WT3, nullptr, nullptr, nullptr, 0, nullptr, Bh0, N + 1);  // M3
    gather64<<<wblk, 256, 0, stream>>>(
        Bh0, cntI, packed, b3, (float*)d_out, N);
}

// Round 3
// 268.994 us; speedup vs baseline: 1.2387x; 1.1061x over previous
//
#include <hip/hip_runtime.h>
#include <math.h>

// ---------------------------------------------------------------------------
// GCN 3x GraphConv (DGL norm='both'), N=50000, E=800000, 256->128->128->64.
// R14: fuse gather128(agg2)+gemm2+gemm3 into ONE kernel (layer23): the only
// adjacent kernels operating on the SAME node rows. Phase A gathers H1s[src]
// sums into LDS agg[128][136] (8 waves x 16 nodes); Phase B stages WT2, MFMA
// from LDS, epilogue (nd,b2,relu,ns), overwrites agg in place with f16 H2s
// (wave-private rows); Phase C restages WT3, MFMA, writes M3. Removes 2
// dispatches + 51.2MB of agg2/H2s round-trip traffic. 7 dispatches.
//   L1: M1 = f16(X*ns)@W1 ; H1s = relu(sum M1[src] *nd + b1)*ns
//   L2+3 (fused): agg2 = sum H1s[src]; H2s = relu((agg2@W2)*nd+b2)*ns;
//                 M3 = H2s@W3 ; out = sum M3[src]*nd + b3 (gather64)
// ---------------------------------------------------------------------------

typedef _Float16 half8 __attribute__((ext_vector_type(8)));
typedef float floatx4 __attribute__((ext_vector_type(4)));

#define TILE  1024   // edges per bin tile (782 blocks)
#define BCAP  8192   // per-coarse-bucket capacity (avg 4096)
#define PKW   64     // packed list width per node = 128B line
#define EPT   4      // edges per thread in bin pass (TILE/256)
#define SPLIT 4      // lists blocks per bucket (64 nodes each)

// ---- pass 1: bin (src,dst) by dst>>8 AND src by src>>8, direct scatter ----
__global__ __launch_bounds__(256) void bin_edges(
    const int* __restrict__ src, const int* __restrict__ dst, int E, int NB,
    int* __restrict__ gcurD, int* __restrict__ gcurS,
    ushort2* __restrict__ binD, unsigned short* __restrict__ binS)
{
    __shared__ int lcntD[256], curD[256];
    __shared__ int lcntS[256], curS[256];

    const int tid = threadIdx.x;
    const int tile0 = blockIdx.x * TILE;
    const int tn = min(TILE, E - tile0);

    lcntD[tid] = 0;
    lcntS[tid] = 0;
    __syncthreads();

    unsigned short es[EPT], ed[EPT];
    unsigned char ebD[EPT], ebS[EPT];
    int nl = 0;
    for (int i = tid; i < tn; i += 256) {
        int s = src[tile0 + i], d = dst[tile0 + i];
        es[nl] = (unsigned short)s; ed[nl] = (unsigned short)d;
        ebD[nl] = (unsigned char)(d >> 8);
        ebS[nl] = (unsigned char)(s >> 8);
        nl++;
        atomicAdd(&lcntD[d >> 8], 1);
        atomicAdd(&lcntS[s >> 8], 1);
    }
    __syncthreads();

    if (tid < NB) {
        curD[tid] = (lcntD[tid] > 0) ? atomicAdd(&gcurD[tid], lcntD[tid]) : 0;
        curS[tid] = (lcntS[tid] > 0) ? atomicAdd(&gcurS[tid], lcntS[tid]) : 0;
    }
    __syncthreads();

    for (int j = 0; j < nl; j++) {
        int bD = ebD[j];
        int pD = atomicAdd(&curD[bD], 1);
        if (pD < BCAP) {
            ushort2 u; u.x = es[j]; u.y = ed[j];
            binD[(size_t)bD * BCAP + pD] = u;
        }
        int bS = ebS[j];
        int pS = atomicAdd(&curS[bS], 1);
        if (pS < BCAP) binS[(size_t)bS * BCAP + pS] = es[j];
    }
}

// ---- pass 2: packed in-lists (pad-filled) + cntI + cntO ----
__global__ __launch_bounds__(256) void lists_counts(
    const ushort2* __restrict__ binD, const int* __restrict__ gcurD,
    const unsigned short* __restrict__ binS, const int* __restrict__ gcurS,
    unsigned short* __restrict__ packed, int* __restrict__ cntI,
    int* __restrict__ cntO, int N, unsigned short padv)
{
    __shared__ unsigned short stage[64 * PKW];   // 8 KB
    __shared__ int lcnt[64];
    __shared__ int h[64];
    const int tid = threadIdx.x;
    const int b = blockIdx.x / SPLIT;
    const int part = blockIdx.x - b * SPLIT;
    const int nlo = (b << 8) + part * 64;        // first node of my 64

    if (tid < 64) { lcnt[tid] = 0; h[tid] = 0; }
    {
        unsigned int pp = (unsigned int)padv | ((unsigned int)padv << 16);
        uint4 v; v.x = pp; v.y = pp; v.z = pp; v.w = pp;
        for (int i = tid; i < 64 * PKW / 8; i += 256)   // 512 x 16B
            ((uint4*)stage)[i] = v;
    }
    __syncthreads();

    const int nD = min(gcurD[b], BCAP);
    const ushort2* ebD = binD + (size_t)b * BCAP;
    for (int i = tid; i < nD; i += 256) {
        ushort2 e = ebD[i];
        int ld = (int)e.y - nlo;
        if ((unsigned)ld < 64u) {
            int p = atomicAdd(&lcnt[ld], 1);
            if (p < PKW) stage[ld * PKW + p] = e.x;
        }
    }
    const int nS = min(gcurS[b], BCAP);
    const unsigned short* ebS = binS + (size_t)b * BCAP;
    for (int i = tid; i < nS; i += 256) {
        int ls = (int)ebS[i] - nlo;
        if ((unsigned)ls < 64u) atomicAdd(&h[ls], 1);
    }
    __syncthreads();

    if (tid < 64) {
        int node = nlo + tid;
        if (node < N) {
            cntI[node] = min(lcnt[tid], PKW);
            cntO[node] = h[tid];
        }
    }
    const int wave = tid >> 6, lane = tid & 63;
    for (int ld = wave; ld < 64; ld += 4) {
        int nd = nlo + ld;
        if (nd < N)
            packed[(size_t)nd * PKW + lane] = stage[ld * PKW + lane];
    }
}

// Fused weight transpose + workspace zeroing:
// gcur (512 ints), Bh0/Bh1 128-wide pad rows (128 halfs each).
__global__ __launch_bounds__(256) void wprep(
    const float* __restrict__ W1, const float* __restrict__ W2,
    const float* __restrict__ W3, _Float16* __restrict__ WT1,
    _Float16* __restrict__ WT2, _Float16* __restrict__ WT3,
    int* __restrict__ gcur, _Float16* __restrict__ z0,
    _Float16* __restrict__ z1)
{
    int i = blockIdx.x * 256 + threadIdx.x;
    if (i < 512) gcur[i] = 0;
    else if (i < 640) z0[i - 512] = (_Float16)0.f;
    else if (i < 768) z1[i - 640] = (_Float16)0.f;
    if (i < 256 * 128) {
        int k = i / 128, n = i - k * 128;
        WT1[(size_t)n * 256 + k] = (_Float16)W1[i];
    } else if (i < 256 * 128 + 128 * 128) {
        int r = i - 256 * 128;
        int k = r / 128, n = r - k * 128;
        WT2[(size_t)n * 128 + k] = (_Float16)W2[r];
    } else if (i < 256 * 128 + 128 * 128 + 128 * 64) {
        int r = i - 256 * 128 - 128 * 128;
        int k = r / 64, n = r - k * 64;
        WT3[(size_t)n * 128 + k] = (_Float16)W3[r];
    }
}

// ---------------------------------------------------------------------------
// LDS-staged MFMA GEMM (verified R9/R10): C[M,NC] f16 = A[M,K] @ WT[NC,K].
// Used for layer 1 only now. Block = 4 waves x 128 rows; wave = 2 m-tiles.
// ---------------------------------------------------------------------------
template<int K, int NC, bool A_FP32>
__global__ __launch_bounds__(256) void gemm_mfma(
    const void* __restrict__ A_, const _Float16* __restrict__ WT,
    const int* __restrict__ cnt_rs,
    const int* __restrict__ cnt_nd, const float* __restrict__ bias,
    int do_relu, const int* __restrict__ cnt_ns,
    _Float16* __restrict__ C, int M)
{
    constexpr int NT  = NC / 16;
    constexpr int KC  = 128;
    constexpr int LDW = KC + 8;
    __shared__ _Float16 Bs[NC * LDW];

    const int tid  = threadIdx.x;
    const int wave = tid >> 6;
    const int lane = tid & 63;
    const int quad = lane >> 4;
    const int l16  = lane & 15;

    const int row_base = blockIdx.x * 128 + wave * 32;
    const int ar0 = min(row_base + l16, M - 1);
    const int ar1 = min(row_base + 16 + l16, M - 1);

    floatx4 acc[2][NT];
#pragma unroll
    for (int m = 0; m < 2; m++)
#pragma unroll
        for (int t = 0; t < NT; t++)
            acc[m][t] = (floatx4){0.f, 0.f, 0.f, 0.f};

    float rs0 = 1.0f, rs1 = 1.0f;
    if (A_FP32 && cnt_rs) {
        rs0 = rsqrtf(fmaxf((float)cnt_rs[ar0], 1.0f));
        rs1 = rsqrtf(fmaxf((float)cnt_rs[ar1], 1.0f));
    }

    const float*    Af = (const float*)A_;
    const _Float16* Ah = (const _Float16*)A_;

    for (int kc = 0; kc < K; kc += KC) {
#pragma unroll
        for (int s = tid; s < NC * (KC / 8); s += 256) {
            int row  = s >> 4;
            int col8 = s & 15;
            half8 v = *(const half8*)&WT[(size_t)row * K + kc + col8 * 8];
            *(half8*)&Bs[row * LDW + col8 * 8] = v;
        }
        __syncthreads();
#pragma unroll
        for (int k0 = 0; k0 < KC; k0 += 32) {
            half8 a0, a1;
            if (A_FP32) {
                const float* p0 = &Af[(size_t)ar0 * K + kc + k0 + quad * 8];
                const float* p1 = &Af[(size_t)ar1 * K + kc + k0 + quad * 8];
                float4 f0 = *(const float4*)p0;
                float4 f1 = *(const float4*)(p0 + 4);
                float4 g0 = *(const float4*)p1;
                float4 g1 = *(const float4*)(p1 + 4);
                a0[0] = (_Float16)(f0.x * rs0); a0[1] = (_Float16)(f0.y * rs0);
                a0[2] = (_Float16)(f0.z * rs0); a0[3] = (_Float16)(f0.w * rs0);
                a0[4] = (_Float16)(f1.x * rs0); a0[5] = (_Float16)(f1.y * rs0);
                a0[6] = (_Float16)(f1.z * rs0); a0[7] = (_Float16)(f1.w * rs0);
                a1[0] = (_Float16)(g0.x * rs1); a1[1] = (_Float16)(g0.y * rs1);
                a1[2] = (_Float16)(g0.z * rs1); a1[3] = (_Float16)(g0.w * rs1);
                a1[4] = (_Float16)(g1.x * rs1); a1[5] = (_Float16)(g1.y * rs1);
                a1[6] = (_Float16)(g1.z * rs1); a1[7] = (_Float16)(g1.w * rs1);
            } else {
                a0 = *(const half8*)&Ah[(size_t)ar0 * K + kc + k0 + quad * 8];
                a1 = *(const half8*)&Ah[(size_t)ar1 * K + kc + k0 + quad * 8];
            }
#pragma unroll
            for (int t = 0; t < NT; t++) {
                half8 b = *(const half8*)&Bs[(t * 16 + l16) * LDW + k0 + quad * 8];
                acc[0][t] = __builtin_amdgcn_mfma_f32_16x16x32_f16(a0, b, acc[0][t], 0, 0, 0);
                acc[1][t] = __builtin_amdgcn_mfma_f32_16x16x32_f16(a1, b, acc[1][t], 0, 0, 0);
            }
        }
        __syncthreads();
    }

#pragma unroll
    for (int m = 0; m < 2; m++) {
#pragma unroll
        for (int t = 0; t < NT; t++) {
            int col = t * 16 + l16;
            float bv = bias ? bias[col] : 0.f;
#pragma unroll
            for (int r = 0; r < 4; r++) {
                int row_o = row_base + m * 16 + quad * 4 + r;
                if (row_o < M) {
                    float v = acc[m][t][r];
                    if (cnt_nd) v *= rsqrtf(fmaxf((float)cnt_nd[row_o], 1.0f));
                    v += bv;
                    if (do_relu) v = fmaxf(v, 0.f);
                    if (cnt_ns) v *= rsqrtf(fmaxf((float)cnt_ns[row_o], 1.0f));
                    C[(size_t)row_o * NC + col] = (_Float16)v;
                }
            }
        }
    }
}

// ---------------------------------------------------------------------------
// Fused layer 2+3: block = 512 thr (8 waves) x 128 nodes.
//  A: gather agg2 = sum H1s[src] into LDS agg[128][136] (wave = 16 nodes).
//  B: H2s = relu((agg@W2)*rsqrt(cntI)+b2)*rsqrt(cntO), in-place to agg (f16).
//  C: M3 = H2s@W3 -> global (f16, 64-wide).
// ---------------------------------------------------------------------------
__global__ __launch_bounds__(512) void layer23(
    const _Float16* __restrict__ H1s, const int* __restrict__ cntI,
    const int* __restrict__ cntO, const unsigned short* __restrict__ packed,
    const _Float16* __restrict__ WT2, const _Float16* __restrict__ WT3,
    const float* __restrict__ b2, _Float16* __restrict__ M3, int N)
{
    constexpr int LDW = 136;            // 128 + 8 halfs
    __shared__ _Float16 agg[128 * LDW]; // 34.8 KB
    __shared__ _Float16 Bs[128 * LDW];  // 34.8 KB

    const int tid  = threadIdx.x;
    const int w    = tid >> 6;
    const int lane = tid & 63;
    const int quad = lane >> 4;
    const int l16  = lane & 15;
    const int grp  = lane >> 4;         // gather group (same as quad)
    const int base = blockIdx.x * 128;

    // zero M3's pad row (row N, 64 halfs) once
    if (blockIdx.x == 0 && tid < 8) {
        half8 zv;
#pragma unroll
        for (int h = 0; h < 8; h++) zv[h] = (_Float16)0.f;
        ((half8*)(M3 + (size_t)N * 64))[tid] = zv;
    }

    // ---- Phase A: gather (wave-per-node, 16 nodes per wave) ----
    const half8* mp = (const half8*)H1s;   // 16 half8 per row
    for (int i = 0; i < 16; i++) {
        const int row  = w * 16 + i;
        const int node = base + row;
        float a[8];
#pragma unroll
        for (int h = 0; h < 8; h++) a[h] = 0.f;
        if (node < N) {
            int len = cntI[node];
            const unsigned short* bl = packed + (size_t)node * PKW;
            int iters = (len + 15) >> 4;
            if (iters < 1) iters = 1;
            for (int it = 0; it < iters; it++) {
                int j = it * 16 + grp;
                int s0 = bl[j], s1 = bl[j + 4], s2 = bl[j + 8], s3 = bl[j + 12];
                half8 v0 = mp[(size_t)s0 * 16 + l16];
                half8 v1 = mp[(size_t)s1 * 16 + l16];
                half8 v2 = mp[(size_t)s2 * 16 + l16];
                half8 v3 = mp[(size_t)s3 * 16 + l16];
#pragma unroll
                for (int h = 0; h < 8; h++)
                    a[h] += ((float)v0[h] + (float)v1[h]) + ((float)v2[h] + (float)v3[h]);
            }
#pragma unroll
            for (int h = 0; h < 8; h++) {
                a[h] += __shfl_xor(a[h], 16);
                a[h] += __shfl_xor(a[h], 32);
            }
        }
        if (grp == 0) {
            half8 rv;
#pragma unroll
            for (int h = 0; h < 8; h++) rv[h] = (_Float16)a[h];
            *(half8*)&agg[row * LDW + l16 * 8] = rv;
        }
    }
    __syncthreads();

    // ---- Phase B: H2 = agg @ W2 (K=128, NC=128), epilogue -> agg in place --
#pragma unroll
    for (int s = tid; s < 128 * 16; s += 512) {
        int row = s >> 4, col8 = s & 15;
        *(half8*)&Bs[row * LDW + col8 * 8] =
            *(const half8*)&WT2[(size_t)row * 128 + col8 * 8];
    }
    __syncthreads();

    floatx4 acc[8];
#pragma unroll
    for (int t = 0; t < 8; t++) acc[t] = (floatx4){0.f, 0.f, 0.f, 0.f};
#pragma unroll
    for (int k0 = 0; k0 < 128; k0 += 32) {
        half8 a0 = *(const half8*)&agg[(w * 16 + l16) * LDW + k0 + quad * 8];
#pragma unroll
        for (int t = 0; t < 8; t++) {
            half8 b = *(const half8*)&Bs[(t * 16 + l16) * LDW + k0 + quad * 8];
            acc[t] = __builtin_amdgcn_mfma_f32_16x16x32_f16(a0, b, acc[t], 0, 0, 0);
        }
    }
    // epilogue: per-row norms (rows quad*4+r of this wave's 16-row tile)
    float rsI_[4], rsO_[4];
#pragma unroll
    for (int r = 0; r < 4; r++) {
        int row_o = base + w * 16 + quad * 4 + r;
        int ro = min(row_o, N - 1);
        rsI_[r] = rsqrtf(fmaxf((float)cntI[ro], 1.0f));
        rsO_[r] = rsqrtf(fmaxf((float)cntO[ro], 1.0f));
    }
#pragma unroll
    for (int t = 0; t < 8; t++) {
        int col = t * 16 + l16;
        float bv = b2[col];
#pragma unroll
        for (int r = 0; r < 4; r++) {
            int row_l = w * 16 + quad * 4 + r;
            float v = acc[t][r] * rsI_[r] + bv;
            v = fmaxf(v, 0.f);
            v *= rsO_[r];
            agg[row_l * LDW + col] = (_Float16)v;   // wave-private rows
        }
    }
    __syncthreads();

    // ---- Phase C: M3 = H2s @ W3 (K=128, NC=64) ----
#pragma unroll
    for (int s = tid; s < 64 * 16; s += 512) {
        int row = s >> 4, col8 = s & 15;
        *(half8*)&Bs[row * LDW + col8 * 8] =
            *(const half8*)&WT3[(size_t)row * 128 + col8 * 8];
    }
    __syncthreads();

    floatx4 acc3[4];
#pragma unroll
    for (int t = 0; t < 4; t++) acc3[t] = (floatx4){0.f, 0.f, 0.f, 0.f};
#pragma unroll
    for (int k0 = 0; k0 < 128; k0 += 32) {
        half8 a0 = *(const half8*)&agg[(w * 16 + l16) * LDW + k0 + quad * 8];
#pragma unroll
        for (int t = 0; t < 4; t++) {
            half8 b = *(const half8*)&Bs[(t * 16 + l16) * LDW + k0 + quad * 8];
            acc3[t] = __builtin_amdgcn_mfma_f32_16x16x32_f16(a0, b, acc3[t], 0, 0, 0);
        }
    }
#pragma unroll
    for (int t = 0; t < 4; t++) {
        int col = t * 16 + l16;
#pragma unroll
        for (int r = 0; r < 4; r++) {
            int row_o = base + w * 16 + quad * 4 + r;
            if (row_o < N)
                M3[(size_t)row_o * 64 + col] = (_Float16)acc3[t][r];
        }
    }
}

// ---------------------------------------------------------------------------
// F=128 gather (layer 1): wave/node, 4 groups x 16 lanes x half8; 16
// slots/iter; epilogue nd + b1 + relu + ns.
// ---------------------------------------------------------------------------
__global__ __launch_bounds__(256) void gather128(
    const _Float16* __restrict__ msg, const int* __restrict__ cntI,
    const int* __restrict__ cntO, const unsigned short* __restrict__ packed,
    const float* __restrict__ bias, int do_relu, int use_nd, int use_ns,
    _Float16* __restrict__ out, int N)
{
    int node = (blockIdx.x * 256 + threadIdx.x) >> 6;
    if (node >= N) return;
    int lane = threadIdx.x & 63;
    int grp = lane >> 4, l16 = lane & 15;

    int len = min(cntI[node], PKW);
    const unsigned short* bl = packed + (size_t)node * PKW;
    const half8* mp = (const half8*)msg;   // 16 half8 per row

    float a[8];
#pragma unroll
    for (int h = 0; h < 8; h++) a[h] = 0.f;

    int iters = (len + 15) >> 4;
    if (iters < 1) iters = 1;
    for (int it = 0; it < iters; it++) {
        int j = it * 16 + grp;
        int s0 = bl[j], s1 = bl[j + 4], s2 = bl[j + 8], s3 = bl[j + 12];
        half8 v0 = mp[(size_t)s0 * 16 + l16];
        half8 v1 = mp[(size_t)s1 * 16 + l16];
        half8 v2 = mp[(size_t)s2 * 16 + l16];
        half8 v3 = mp[(size_t)s3 * 16 + l16];
#pragma unroll
        for (int h = 0; h < 8; h++)
            a[h] += ((float)v0[h] + (float)v1[h]) + ((float)v2[h] + (float)v3[h]);
    }
#pragma unroll
    for (int h = 0; h < 8; h++) {
        a[h] += __shfl_xor(a[h], 16);
        a[h] += __shfl_xor(a[h], 32);
    }

    if (grp == 0) {
        float sc = use_nd ? rsqrtf(fmaxf((float)len, 1.0f)) : 1.0f;
        float pp = use_ns ? rsqrtf(fmaxf((float)cntO[node], 1.0f)) : 1.0f;
        half8 rv;
#pragma unroll
        for (int h = 0; h < 8; h++) {
            float bv = bias ? bias[l16 * 8 + h] : 0.f;
            float r = a[h] * sc + bv;
            if (do_relu) r = fmaxf(r, 0.f);
            rv[h] = (_Float16)(r * pp);
        }
        ((half8*)out)[(size_t)node * 16 + l16] = rv;
    }
}

// F=64 gather: 8 groups x 8 lanes x half8; 16 slots/iter; fp32 out.
__global__ __launch_bounds__(256) void gather64(
    const _Float16* __restrict__ msg, const int* __restrict__ cntI,
    const unsigned short* __restrict__ packed, const float* __restrict__ bias,
    float* __restrict__ out, int N)
{
    int node = (blockIdx.x * 256 + threadIdx.x) >> 6;
    if (node >= N) return;
    int lane = threadIdx.x & 63;
    int grp = lane >> 3, l8 = lane & 7;

    int len = min(cntI[node], PKW);
    const unsigned short* bl = packed + (size_t)node * PKW;
    const half8* mp = (const half8*)msg;   // 8 half8 per row

    float a[8];
#pragma unroll
    for (int h = 0; h < 8; h++) a[h] = 0.f;

    int iters = (len + 15) >> 4;
    if (iters < 1) iters = 1;
    for (int it = 0; it < iters; it++) {
        int j = it * 16 + grp;
        int s0 = bl[j], s1 = bl[j + 8];
        half8 v0 = mp[(size_t)s0 * 8 + l8];
        half8 v1 = mp[(size_t)s1 * 8 + l8];
#pragma unroll
        for (int h = 0; h < 8; h++)
            a[h] += (float)v0[h] + (float)v1[h];
    }
#pragma unroll
    for (int h = 0; h < 8; h++) {
        a[h] += __shfl_xor(a[h], 8);
        a[h] += __shfl_xor(a[h], 16);
        a[h] += __shfl_xor(a[h], 32);
    }

    if (grp == 0) {
        float sc = rsqrtf(fmaxf((float)len, 1.0f));
        float4 r0, r1;
        r0.x = a[0] * sc + bias[l8 * 8 + 0];
        r0.y = a[1] * sc + bias[l8 * 8 + 1];
        r0.z = a[2] * sc + bias[l8 * 8 + 2];
        r0.w = a[3] * sc + bias[l8 * 8 + 3];
        r1.x = a[4] * sc + bias[l8 * 8 + 4];
        r1.y = a[5] * sc + bias[l8 * 8 + 5];
        r1.z = a[6] * sc + bias[l8 * 8 + 6];
        r1.w = a[7] * sc + bias[l8 * 8 + 7];
        float4* op = (float4*)&out[(size_t)node * 64 + l8 * 8];
        op[0] = r0;
        op[1] = r1;
    }
}

extern "C" void kernel_launch(void* const* d_in, const int* in_sizes, int n_in,
                              void* d_out, int out_size, void* d_ws, size_t ws_size,
                              hipStream_t stream)
{
    const float* X  = (const float*)d_in[0];
    const float* W1 = (const float*)d_in[1];
    const float* b1 = (const float*)d_in[2];
    const float* W2 = (const float*)d_in[3];
    const float* b2 = (const float*)d_in[4];
    const float* W3 = (const float*)d_in[5];
    const float* b3 = (const float*)d_in[6];
    const int*   src = (const int*)d_in[7];
    const int*   dst = (const int*)d_in[8];

    const int N = in_sizes[0] / 256;   // 50000
    const int E = in_sizes[7];         // 800000
    const int NB = (N + 255) >> 8;     // 196 coarse buckets

    char* base = (char*)d_ws;
    size_t cur = 0;
    auto alloc = [&](size_t bytes) -> void* {
        void* p = base + cur;
        cur += (bytes + 255) & ~(size_t)255;
        return p;
    };
    int* gcur2 = (int*)alloc((size_t)2 * 256 * 4);
    int* gcurD = gcur2;
    int* gcurS = gcur2 + 256;
    ushort2*        binD   = (ushort2*)alloc((size_t)NB * BCAP * 4);
    unsigned short* binS   = (unsigned short*)alloc((size_t)NB * BCAP * 2);
    unsigned short* packed = (unsigned short*)alloc((size_t)N * PKW * 2);
    int* cntO = (int*)alloc((size_t)N * 4);
    int* cntI = (int*)alloc((size_t)N * 4);
    _Float16* Bh0 = (_Float16*)alloc(((size_t)N + 1) * 128 * 2);  // M1 / M3
    _Float16* Bh1 = (_Float16*)alloc(((size_t)N + 1) * 128 * 2);  // H1s
    _Float16* WT1 = (_Float16*)alloc((size_t)256 * 128 * 2);
    _Float16* WT2 = (_Float16*)alloc((size_t)128 * 128 * 2);
    _Float16* WT3 = (_Float16*)alloc((size_t)128 * 64 * 2);

    const int tblk = (E + TILE - 1) / TILE;   // 782 tiles
    const int gblk = (N + 127) / 128;
    const int wblk = (N + 3) / 4;

    wprep<<<(256*128 + 128*128 + 128*64 + 255) / 256, 256, 0, stream>>>(
        W1, W2, W3, WT1, WT2, WT3,
        gcur2, Bh0 + (size_t)N * 128, Bh1 + (size_t)N * 128);
    bin_edges<<<tblk, 256, 0, stream>>>(src, dst, E, NB, gcurD, gcurS, binD, binS);
    lists_counts<<<NB * SPLIT, 256, 0, stream>>>(binD, gcurD, binS, gcurS,
                                                 packed, cntI, cntO, N,
                                                 (unsigned short)N);

    // ---- Layer 1 ----
    gemm_mfma<256, 128, true><<<gblk, 256, 0, stream>>>(
        X, WT1, cntO, nullptr, nullptr, 0, nullptr, Bh0, N);          // M1
    gather128<<<wblk, 256, 0, stream>>>(
        Bh0, cntI, cntO, packed, b1, 1, 1, 1, Bh1, N);                // H1s

    // ---- Layers 2+3 fused (M3 overwrites Bh0 as 64-wide; pad row zeroed
    //      by block 0 inside the kernel) ----
    layer23<<<gblk, 512, 0, stream>>>(
        Bh1, cntI, cntO, packed, WT2, WT3, b2, Bh0, N);               // M3

    gather64<<<wblk, 256, 0, stream>>>(
        Bh0, cntI, packed, b3, (float*)d_out, N);
}